// Round 4
// baseline (1169.848 us; speedup 1.0000x reference)
//
#include <hip/hip_runtime.h>
#include <hip/hip_bf16.h>
#include <stdint.h>

#define DM    1024
#define NH    16
#define HS    64
#define S_LEN 2048
#define NB    2
#define M_ROWS 4096  // NB * S_LEN

__device__ __forceinline__ uint16_t f2b(float f) {
    union { float f; uint32_t i; } x; x.f = f;
    uint32_t r = x.i + 0x7fffu + ((x.i >> 16) & 1u);
    return (uint16_t)(r >> 16);
}
__device__ __forceinline__ float2 b2x2(uint32_t u) {
    union { uint32_t i; float f; } lo, hi;
    lo.i = u << 16; hi.i = u & 0xffff0000u;
    return make_float2(lo.f, hi.f);
}

// -------- Tiled GEMM: C(M x N) = A(M x K=1024) @ W(K x N) + bias --------
// A dtype: fp32 (ABF=false) or bf16 (ABF=true). W/bias fp32.
// MODE 0: N=3072 fused epilogue (split qkv, RoPE; k/v -> fp32 d_out, rotated
//         q/k -> bf16 ws). MODE 1: plain fp32 C out.
template<int MODE, bool ABF>
__global__ __launch_bounds__(256) void gemm_kernel(
    const void* __restrict__ Araw,
    const float* __restrict__ W,
    const float* __restrict__ bias,
    int N,
    const float* __restrict__ cq, const float* __restrict__ sq,
    const float* __restrict__ ck, const float* __restrict__ sk,
    uint16_t* __restrict__ qbuf, uint16_t* __restrict__ kbuf,
    float* __restrict__ kout, float* __restrict__ vout,
    float* __restrict__ Cout)
{
    const int K = DM;
    __shared__ float As[16][68];  // transposed: As[k][m]
    __shared__ float Bs[16][68];  // Bs[k][n]

    const int tid = threadIdx.x;
    const int tx = tid & 15, ty = tid >> 4;
    const int m0 = blockIdx.y * 64;
    const int n0 = blockIdx.x * 64;

    float acc[4][4] = {};

    const int arow = tid >> 2;        // 0..63 (m)
    const int akc  = (tid & 3) * 4;   // k-chunk 0,4,8,12
    const int brow = tid >> 4;        // 0..15 (k)
    const int bnc  = (tid & 15) * 4;  // n-chunk

    for (int k0 = 0; k0 < K; k0 += 16) {
        float a0, a1, a2, a3;
        if (ABF) {
            const uint16_t* A = (const uint16_t*)Araw;
            uint2 av = *(const uint2*)(A + (size_t)(m0 + arow) * K + k0 + akc);
            float2 p0 = b2x2(av.x), p1 = b2x2(av.y);
            a0 = p0.x; a1 = p0.y; a2 = p1.x; a3 = p1.y;
        } else {
            const float* A = (const float*)Araw;
            float4 av = *(const float4*)(A + (size_t)(m0 + arow) * K + k0 + akc);
            a0 = av.x; a1 = av.y; a2 = av.z; a3 = av.w;
        }
        float4 bv = *(const float4*)(W + (size_t)(k0 + brow) * N + n0 + bnc);
        __syncthreads();  // previous tile's compute done before overwrite
        As[akc + 0][arow] = a0;
        As[akc + 1][arow] = a1;
        As[akc + 2][arow] = a2;
        As[akc + 3][arow] = a3;
        *(float4*)(&Bs[brow][bnc]) = bv;
        __syncthreads();
        #pragma unroll
        for (int k = 0; k < 16; ++k) {
            float4 a = *(const float4*)(&As[k][ty * 4]);
            float4 b = *(const float4*)(&Bs[k][tx * 4]);
            float a_[4] = {a.x, a.y, a.z, a.w};
            float b_[4] = {b.x, b.y, b.z, b.w};
            #pragma unroll
            for (int r = 0; r < 4; ++r)
                #pragma unroll
                for (int c = 0; c < 4; ++c)
                    acc[r][c] += a_[r] * b_[c];
        }
    }

    const int mrow = m0 + ty * 4;
    const int ncol = n0 + tx * 4;

    if (MODE == 1) {
        #pragma unroll
        for (int r = 0; r < 4; ++r) {
            size_t base = (size_t)(mrow + r) * N + ncol;
            #pragma unroll
            for (int c = 0; c < 4; ++c)
                Cout[base + c] = acc[r][c] + bias[ncol + c];
        }
    } else {
        const int sel = ncol >> 10;        // 0=q 1=k 2=v
        const int d   = ncol & 1023;
        const int h   = d >> 6;
        const int hd  = d & 63;            // 4-aligned -> RoPE pairs stay in-thread
        const int i0  = hd >> 1;
        #pragma unroll
        for (int r = 0; r < 4; ++r) {
            int m = mrow + r;
            int b = m >> 11;               // m / S_LEN
            int s = m & 2047;
            float v0 = acc[r][0] + bias[ncol + 0];
            float v1 = acc[r][1] + bias[ncol + 1];
            float v2 = acc[r][2] + bias[ncol + 2];
            float v3 = acc[r][3] + bias[ncol + 3];
            size_t idx = ((size_t)(b * NH + h) * S_LEN + s) * HS + hd;
            if (sel == 0) {
                float c0 = cq[s * 32 + i0],     s0 = sq[s * 32 + i0];
                float c1 = cq[s * 32 + i0 + 1], s1 = sq[s * 32 + i0 + 1];
                qbuf[idx + 0] = f2b(v0 * c0 - v1 * s0);
                qbuf[idx + 1] = f2b(v0 * s0 + v1 * c0);
                qbuf[idx + 2] = f2b(v2 * c1 - v3 * s1);
                qbuf[idx + 3] = f2b(v2 * s1 + v3 * c1);
            } else if (sel == 1) {
                kout[idx + 0] = v0; kout[idx + 1] = v1;   // kv[0] = pre-rotary k (fp32)
                kout[idx + 2] = v2; kout[idx + 3] = v3;
                float c0 = ck[s * 32 + i0],     s0 = sk[s * 32 + i0];
                float c1 = ck[s * 32 + i0 + 1], s1 = sk[s * 32 + i0 + 1];
                kbuf[idx + 0] = f2b(v0 * c0 - v1 * s0);
                kbuf[idx + 1] = f2b(v0 * s0 + v1 * c0);
                kbuf[idx + 2] = f2b(v2 * c1 - v3 * s1);
                kbuf[idx + 3] = f2b(v2 * s1 + v3 * c1);
            } else {
                vout[idx + 0] = v0; vout[idx + 1] = v1;   // kv[1] = v (fp32)
                vout[idx + 2] = v2; vout[idx + 3] = v3;
            }
        }
    }
}

// -------- Flash attention: one block = one (b,h) x 64-query tile --------
// Q,K from bf16 ws; V from fp32 d_out; O -> bf16 ws.
__global__ __launch_bounds__(256) void attn_kernel(
    const uint16_t* __restrict__ qbuf,
    const uint16_t* __restrict__ kbuf,
    const float* __restrict__ vbuf,
    uint16_t* __restrict__ obuf)   // (B, S, DM) bf16
{
    const int qt = blockIdx.x & 31;
    const int bh = blockIdx.x >> 5;   // b*NH + h
    const int h  = bh & 15;
    const int b  = bh >> 4;
    const int tid = threadIdx.x;
    const int tx = tid & 15, ty = tid >> 4;

    __shared__ uint16_t Qs[64][66];
    __shared__ uint16_t Ks[64][66];
    __shared__ uint16_t Vs[64][66];
    __shared__ float    Ps[64][68];

    {   // load Q tile (contiguous 8 KB)
        const uint16_t* qb = qbuf + ((size_t)bh * S_LEN + qt * 64) * HS;
        #pragma unroll
        for (int it = 0; it < 2; ++it) {
            int e = (tid + it * 256) * 8;
            int row = e >> 6, col = e & 63;
            uint4 u = *(const uint4*)(qb + e);
            const uint32_t* p = (const uint32_t*)&u;
            #pragma unroll
            for (int j = 0; j < 4; ++j)
                *(uint32_t*)(&Qs[row][col + j * 2]) = p[j];
        }
    }

    float m_i[4], l_i[4], Oc[4][4];
    #pragma unroll
    for (int r = 0; r < 4; ++r) {
        m_i[r] = -1e30f; l_i[r] = 0.f;
        #pragma unroll
        for (int c = 0; c < 4; ++c) Oc[r][c] = 0.f;
    }

    for (int kt = 0; kt <= qt; ++kt) {
        __syncthreads();  // prior PV done with Vs/Ps; Qs ready (kt=0)
        {
            const uint16_t* kb = kbuf + ((size_t)bh * S_LEN + kt * 64) * HS;
            const float*    vb = vbuf + ((size_t)bh * S_LEN + kt * 64) * HS;
            #pragma unroll
            for (int it = 0; it < 2; ++it) {
                int e = (tid + it * 256) * 8;
                int row = e >> 6, col = e & 63;
                uint4 uk = *(const uint4*)(kb + e);
                float4 vA = *(const float4*)(vb + e);
                float4 vB = *(const float4*)(vb + e + 4);
                const uint32_t* pk = (const uint32_t*)&uk;
                #pragma unroll
                for (int j = 0; j < 4; ++j)
                    *(uint32_t*)(&Ks[row][col + j * 2]) = pk[j];
                uint32_t pv[4];
                pv[0] = (uint32_t)f2b(vA.x) | ((uint32_t)f2b(vA.y) << 16);
                pv[1] = (uint32_t)f2b(vA.z) | ((uint32_t)f2b(vA.w) << 16);
                pv[2] = (uint32_t)f2b(vB.x) | ((uint32_t)f2b(vB.y) << 16);
                pv[3] = (uint32_t)f2b(vB.z) | ((uint32_t)f2b(vB.w) << 16);
                #pragma unroll
                for (int j = 0; j < 4; ++j)
                    *(uint32_t*)(&Vs[row][col + j * 2]) = pv[j];
            }
        }
        __syncthreads();

        // S = Q K^T (4x4 per thread)
        float sc[4][4] = {};
        #pragma unroll 8
        for (int d = 0; d < 64; d += 2) {
            float2 qv[4], kv[4];
            #pragma unroll
            for (int r = 0; r < 4; ++r)
                qv[r] = b2x2(*(const uint32_t*)(&Qs[ty * 4 + r][d]));
            #pragma unroll
            for (int c = 0; c < 4; ++c)
                kv[c] = b2x2(*(const uint32_t*)(&Ks[tx * 4 + c][d]));
            #pragma unroll
            for (int r = 0; r < 4; ++r)
                #pragma unroll
                for (int c = 0; c < 4; ++c)
                    sc[r][c] += qv[r].x * kv[c].x + qv[r].y * kv[c].y;
        }

        const int gq0 = qt * 64 + ty * 4;
        const int gk0 = kt * 64 + tx * 4;
        float pr[4][4];
        #pragma unroll
        for (int r = 0; r < 4; ++r) {
            float mx = -1e30f;
            #pragma unroll
            for (int c = 0; c < 4; ++c) {
                float v = sc[r][c] * 0.125f;           // 1/sqrt(64)
                if (gk0 + c > gq0 + r) v = -65504.f;   // causal (MIN_FP16)
                sc[r][c] = v;
                mx = fmaxf(mx, v);
            }
            mx = fmaxf(mx, __shfl_xor(mx, 1, 16));
            mx = fmaxf(mx, __shfl_xor(mx, 2, 16));
            mx = fmaxf(mx, __shfl_xor(mx, 4, 16));
            mx = fmaxf(mx, __shfl_xor(mx, 8, 16));
            float mnew  = fmaxf(m_i[r], mx);
            float alpha = __expf(m_i[r] - mnew);
            m_i[r] = mnew;
            float rs = 0.f;
            #pragma unroll
            for (int c = 0; c < 4; ++c) {
                float p = __expf(sc[r][c] - mnew);
                pr[r][c] = p;
                rs += p;
            }
            rs += __shfl_xor(rs, 1, 16);
            rs += __shfl_xor(rs, 2, 16);
            rs += __shfl_xor(rs, 4, 16);
            rs += __shfl_xor(rs, 8, 16);
            l_i[r] = l_i[r] * alpha + rs;
            #pragma unroll
            for (int c = 0; c < 4; ++c) Oc[r][c] *= alpha;
        }

        #pragma unroll
        for (int r = 0; r < 4; ++r)
            #pragma unroll
            for (int c = 0; c < 4; ++c)
                Ps[ty * 4 + r][tx * 4 + c] = pr[r][c];
        __syncthreads();

        // Oc += P @ V
        #pragma unroll 4
        for (int j = 0; j < 64; ++j) {
            float pj[4];
            #pragma unroll
            for (int r = 0; r < 4; ++r) pj[r] = Ps[ty * 4 + r][j];
            float2 v01 = b2x2(*(const uint32_t*)(&Vs[j][tx * 4]));
            float2 v23 = b2x2(*(const uint32_t*)(&Vs[j][tx * 4 + 2]));
            float vv[4] = {v01.x, v01.y, v23.x, v23.y};
            #pragma unroll
            for (int r = 0; r < 4; ++r)
                #pragma unroll
                for (int c = 0; c < 4; ++c)
                    Oc[r][c] += pj[r] * vv[c];
        }
    }

    #pragma unroll
    for (int r = 0; r < 4; ++r) {
        float inv = 1.f / l_i[r];
        int s = qt * 64 + ty * 4 + r;
        size_t base = ((size_t)b * S_LEN + s) * DM + h * HS + tx * 4;
        #pragma unroll
        for (int c = 0; c < 4; ++c)
            obuf[base + c] = f2b(Oc[r][c] * inv);
    }
}

extern "C" void kernel_launch(void* const* d_in, const int* in_sizes, int n_in,
                              void* d_out, int out_size, void* d_ws, size_t ws_size,
                              hipStream_t stream) {
    const float* x  = (const float*)d_in[0];
    const float* cq = (const float*)d_in[1];
    const float* sq = (const float*)d_in[2];
    const float* ck = (const float*)d_in[3];
    const float* sk = (const float*)d_in[4];
    // d_in[5]: causal tril mask (int32) — structure known, not re-read
    const float* Wp = (const float*)d_in[6];
    const float* bp = (const float*)d_in[7];
    const float* Wf = (const float*)d_in[8];
    const float* bf = (const float*)d_in[9];

    float* out  = (float*)d_out;
    float* ffo  = out;                 // (B,S,DM) fp32
    float* kout = out + 4194304;       // kv[0] = pre-rotary k, (B,NH,S,HS) fp32
    float* vout = out + 8388608;       // kv[1] = v, fp32

    uint16_t* qbuf = (uint16_t*)d_ws;  // RoPE'd q, (B,NH,S,HS) bf16
    uint16_t* kbuf = qbuf + 4194304;   // RoPE'd k, bf16
    uint16_t* abuf = kbuf + 4194304;   // attn_o, (B,S,DM) bf16

    dim3 blk(256);
    gemm_kernel<0, false><<<dim3(3072 / 64, M_ROWS / 64), blk, 0, stream>>>(
        x, Wp, bp, 3072, cq, sq, ck, sk,
        qbuf, kbuf, kout, vout, nullptr);
    attn_kernel<<<dim3(NB * NH * (S_LEN / 64)), blk, 0, stream>>>(
        qbuf, kbuf, vout, abuf);
    gemm_kernel<1, true><<<dim3(DM / 64, M_ROWS / 64), blk, 0, stream>>>(
        abuf, Wf, bf, DM, nullptr, nullptr, nullptr, nullptr,
        nullptr, nullptr, nullptr, nullptr, ffo);
}

// Round 5
// 342.067 us; speedup vs baseline: 3.4199x; 3.4199x over previous
//
#include <hip/hip_runtime.h>
#include <stdint.h>

#define DM    1024
#define NH    16
#define HS    64
#define S_LEN 2048
#define NB    2

typedef short bf16x8 __attribute__((ext_vector_type(8)));
typedef float f32x4  __attribute__((ext_vector_type(4)));

__device__ __forceinline__ uint16_t f2b(float f) {
    union { float f; uint32_t i; } x; x.f = f;
    uint32_t r = x.i + 0x7fffu + ((x.i >> 16) & 1u);
    return (uint16_t)(r >> 16);
}
__device__ __forceinline__ uint32_t pack2(float a, float b) {
    return (uint32_t)f2b(a) | ((uint32_t)f2b(b) << 16);
}
__device__ __forceinline__ f32x4 mfma16(bf16x8 a, bf16x8 b, f32x4 c) {
    return __builtin_amdgcn_mfma_f32_16x16x32_bf16(a, b, c, 0, 0, 0);
}

// ---- One-time W (K=1024 x N fp32) -> WT (N x 1024 bf16) transpose ----
__global__ __launch_bounds__(256) void transpose_w(
    const float* __restrict__ W, uint16_t* __restrict__ WT, int N)
{
    __shared__ float T[32][33];
    const int tx = threadIdx.x & 31, ty = threadIdx.x >> 5;
    const int n0 = blockIdx.x * 32, k0 = blockIdx.y * 32;
    #pragma unroll
    for (int i = 0; i < 4; ++i)
        T[ty + i * 8][tx] = W[(size_t)(k0 + ty + i * 8) * N + n0 + tx];
    __syncthreads();
    #pragma unroll
    for (int i = 0; i < 4; ++i)
        WT[(size_t)(n0 + ty + i * 8) * 1024 + k0 + tx] = f2b(T[tx][ty + i * 8]);
}

// ---- MFMA GEMM: C(M x N) = A(M x 1024) @ BT^T + bias ----
// BT is N x 1024 bf16 (pre-transposed W). A: fp32 (ABF=false) or bf16 (true).
// MODE 0: N=3072 fused RoPE/split epilogue. MODE 1: plain fp32 out.
template<int MODE, bool ABF>
__global__ __launch_bounds__(256) void gemm_mfma(
    const void* __restrict__ Araw,
    const uint16_t* __restrict__ BT,
    const float* __restrict__ bias,
    int N,
    const float* __restrict__ cq, const float* __restrict__ sq,
    const float* __restrict__ ck, const float* __restrict__ sk,
    uint16_t* __restrict__ qbuf, uint16_t* __restrict__ kbuf,
    float* __restrict__ kout, float* __restrict__ vout,
    float* __restrict__ Cout)
{
    __shared__ uint16_t As[128][40];   // [m][k] pad->free-ish frag reads
    __shared__ uint16_t Bs[128][40];   // [n][k]

    const int tid  = threadIdx.x;
    const int wave = tid >> 6, lane = tid & 63;
    const int quad = lane >> 4, li = lane & 15;
    const int wm = (wave >> 1) * 64, wn = (wave & 1) * 64;
    const int m0 = blockIdx.y * 128, n0 = blockIdx.x * 128;

    f32x4 acc[4][4];
    #pragma unroll
    for (int a = 0; a < 4; ++a)
        #pragma unroll
        for (int c = 0; c < 4; ++c)
            acc[a][c] = (f32x4){0.f, 0.f, 0.f, 0.f};

    const int sm = tid >> 1, skc = (tid & 1) * 16;

    for (int k0 = 0; k0 < 1024; k0 += 32) {
        uint4 aw0, aw1;
        if (ABF) {
            const uint16_t* ap = (const uint16_t*)Araw + (size_t)(m0 + sm) * 1024 + k0 + skc;
            aw0 = *(const uint4*)ap;
            aw1 = *(const uint4*)(ap + 8);
        } else {
            const float* ap = (const float*)Araw + (size_t)(m0 + sm) * 1024 + k0 + skc;
            float4 f0 = *(const float4*)(ap + 0),  f1 = *(const float4*)(ap + 4);
            float4 f2 = *(const float4*)(ap + 8),  f3 = *(const float4*)(ap + 12);
            aw0.x = pack2(f0.x, f0.y); aw0.y = pack2(f0.z, f0.w);
            aw0.z = pack2(f1.x, f1.y); aw0.w = pack2(f1.z, f1.w);
            aw1.x = pack2(f2.x, f2.y); aw1.y = pack2(f2.z, f2.w);
            aw1.z = pack2(f3.x, f3.y); aw1.w = pack2(f3.z, f3.w);
        }
        const uint16_t* bp = BT + (size_t)(n0 + sm) * 1024 + k0 + skc;
        uint4 bw0 = *(const uint4*)bp;
        uint4 bw1 = *(const uint4*)(bp + 8);

        __syncthreads();
        *(uint4*)&As[sm][skc]     = aw0;
        *(uint4*)&As[sm][skc + 8] = aw1;
        *(uint4*)&Bs[sm][skc]     = bw0;
        *(uint4*)&Bs[sm][skc + 8] = bw1;
        __syncthreads();

        bf16x8 af[4], bf[4];
        #pragma unroll
        for (int mi = 0; mi < 4; ++mi)
            af[mi] = *(const bf16x8*)&As[wm + mi * 16 + li][quad * 8];
        #pragma unroll
        for (int ni = 0; ni < 4; ++ni)
            bf[ni] = *(const bf16x8*)&Bs[wn + ni * 16 + li][quad * 8];
        #pragma unroll
        for (int mi = 0; mi < 4; ++mi)
            #pragma unroll
            for (int ni = 0; ni < 4; ++ni)
                acc[mi][ni] = mfma16(af[mi], bf[ni], acc[mi][ni]);
    }

    if (MODE == 1) {
        #pragma unroll
        for (int ni = 0; ni < 4; ++ni) {
            const int n = n0 + wn + ni * 16 + li;
            const float bb = bias[n];
            #pragma unroll
            for (int mi = 0; mi < 4; ++mi)
                #pragma unroll
                for (int r = 0; r < 4; ++r) {
                    const int m = m0 + wm + mi * 16 + quad * 4 + r;
                    Cout[(size_t)m * N + n] = acc[mi][ni][r] + bb;
                }
        }
    } else {
        #pragma unroll
        for (int ni = 0; ni < 4; ++ni) {
            const int n   = n0 + wn + ni * 16 + li;
            const int sel = n >> 10;        // 0=q 1=k 2=v (wave-uniform per ni)
            const int d   = n & 1023;
            const int h   = d >> 6;
            const int hd  = d & 63;
            const int i0  = hd >> 1;
            const float bb = bias[n];
            #pragma unroll
            for (int mi = 0; mi < 4; ++mi)
                #pragma unroll
                for (int r = 0; r < 4; ++r) {
                    const int m = m0 + wm + mi * 16 + quad * 4 + r;
                    const int b = m >> 11;
                    const int s = m & 2047;
                    const float val  = acc[mi][ni][r] + bb;
                    const float part = __shfl_xor(val, 1);   // RoPE partner (n^1)
                    const size_t idx = ((size_t)(b * NH + h) * S_LEN + s) * HS + hd;
                    if (sel == 0) {
                        float c = cq[s * 32 + i0], sn = sq[s * 32 + i0];
                        float o = (hd & 1) ? (part * sn + val * c) : (val * c - part * sn);
                        qbuf[idx] = f2b(o);
                    } else if (sel == 1) {
                        kout[idx] = val;                     // kv[0] = pre-rotary k
                        float c = ck[s * 32 + i0], sn = sk[s * 32 + i0];
                        float o = (hd & 1) ? (part * sn + val * c) : (val * c - part * sn);
                        kbuf[idx] = f2b(o);
                    } else {
                        vout[idx] = val;                     // kv[1] = v
                    }
                }
        }
    }
}

// ---- MFMA flash attention: block = (b,h) x 64-query tile, 4 waves x 16 rows ----
__global__ __launch_bounds__(256) void attn_mfma(
    const uint16_t* __restrict__ qbuf,
    const uint16_t* __restrict__ kbuf,
    const float* __restrict__ vbuf,
    uint16_t* __restrict__ obuf)
{
    __shared__ uint16_t Qs[64][72];
    __shared__ uint16_t Ks[64][72];
    __shared__ uint16_t Vt[64][72];   // [hs][key]
    __shared__ uint16_t Ps[64][72];   // wave-private 16-row slabs

    const int i  = blockIdx.x;
    const int bh = i >> 5;
    const int jj = i & 31;
    const int qt = (jj & 1) ? (31 - (jj >> 1)) : (jj >> 1);  // load-balance pairing
    const int h = bh & 15, b = bh >> 4;
    const int tid = threadIdx.x;
    const int wave = tid >> 6, lane = tid & 63;
    const int quad = lane >> 4, li = lane & 15;
    const int wrow0 = wave * 16;

    {   // stage Q once
        const int row = tid >> 2, c = (tid & 3) * 16;
        const uint16_t* qp = qbuf + ((size_t)bh * S_LEN + qt * 64 + row) * HS + c;
        *(uint4*)&Qs[row][c]     = *(const uint4*)qp;
        *(uint4*)&Qs[row][c + 8] = *(const uint4*)(qp + 8);
    }

    f32x4 oacc[4];
    float m_i[4], l_i[4];
    #pragma unroll
    for (int r = 0; r < 4; ++r) {
        m_i[r] = -1e30f; l_i[r] = 0.f;
        oacc[r] = (f32x4){0.f, 0.f, 0.f, 0.f};
    }

    for (int kt = 0; kt <= qt; ++kt) {
        __syncthreads();
        {   // stage K tile
            const int row = tid >> 2, c = (tid & 3) * 16;
            const uint16_t* kp = kbuf + ((size_t)bh * S_LEN + kt * 64 + row) * HS + c;
            *(uint4*)&Ks[row][c]     = *(const uint4*)kp;
            *(uint4*)&Ks[row][c + 8] = *(const uint4*)(kp + 8);
        }
        {   // stage V transposed (fp32 -> bf16)
            const int h0 = (tid >> 5) * 8, kp2 = (tid & 31) * 2;
            const float* vp = vbuf + ((size_t)bh * S_LEN + kt * 64 + kp2) * HS + h0;
            float4 r0a = *(const float4*)vp,        r0b = *(const float4*)(vp + 4);
            float4 r1a = *(const float4*)(vp + HS), r1b = *(const float4*)(vp + HS + 4);
            *(uint32_t*)&Vt[h0 + 0][kp2] = pack2(r0a.x, r1a.x);
            *(uint32_t*)&Vt[h0 + 1][kp2] = pack2(r0a.y, r1a.y);
            *(uint32_t*)&Vt[h0 + 2][kp2] = pack2(r0a.z, r1a.z);
            *(uint32_t*)&Vt[h0 + 3][kp2] = pack2(r0a.w, r1a.w);
            *(uint32_t*)&Vt[h0 + 4][kp2] = pack2(r0b.x, r1b.x);
            *(uint32_t*)&Vt[h0 + 5][kp2] = pack2(r0b.y, r1b.y);
            *(uint32_t*)&Vt[h0 + 6][kp2] = pack2(r0b.z, r1b.z);
            *(uint32_t*)&Vt[h0 + 7][kp2] = pack2(r0b.w, r1b.w);
        }
        __syncthreads();

        // S = Q K^T  (wave's 16 rows x 64 keys)
        bf16x8 aq0 = *(const bf16x8*)&Qs[wrow0 + li][quad * 8];
        bf16x8 aq1 = *(const bf16x8*)&Qs[wrow0 + li][32 + quad * 8];
        f32x4 sacc[4];
        #pragma unroll
        for (int ni = 0; ni < 4; ++ni) {
            bf16x8 b0 = *(const bf16x8*)&Ks[ni * 16 + li][quad * 8];
            bf16x8 b1 = *(const bf16x8*)&Ks[ni * 16 + li][32 + quad * 8];
            f32x4 z = (f32x4){0.f, 0.f, 0.f, 0.f};
            z = mfma16(aq0, b0, z);
            sacc[ni] = mfma16(aq1, b1, z);
        }

        // online softmax (C-layout: row = quad*4+r, col = ni*16+li)
        const bool diag = (kt == qt);
        float p[4][4];
        #pragma unroll
        for (int ni = 0; ni < 4; ++ni)
            #pragma unroll
            for (int r = 0; r < 4; ++r) {
                float v = sacc[ni][r] * 0.125f;     // 1/sqrt(64)
                if (diag && (ni * 16 + li > wrow0 + quad * 4 + r)) v = -65504.f;
                p[ni][r] = v;
            }
        #pragma unroll
        for (int r = 0; r < 4; ++r) {
            float mx = fmaxf(fmaxf(p[0][r], p[1][r]), fmaxf(p[2][r], p[3][r]));
            mx = fmaxf(mx, __shfl_xor(mx, 1));
            mx = fmaxf(mx, __shfl_xor(mx, 2));
            mx = fmaxf(mx, __shfl_xor(mx, 4));
            mx = fmaxf(mx, __shfl_xor(mx, 8));
            float mnew  = fmaxf(m_i[r], mx);
            float alpha = __expf(m_i[r] - mnew);
            m_i[r] = mnew;
            float rs = 0.f;
            #pragma unroll
            for (int ni = 0; ni < 4; ++ni) {
                float e = __expf(p[ni][r] - mnew);
                p[ni][r] = e;
                rs += e;
            }
            rs += __shfl_xor(rs, 1);
            rs += __shfl_xor(rs, 2);
            rs += __shfl_xor(rs, 4);
            rs += __shfl_xor(rs, 8);
            l_i[r] = l_i[r] * alpha + rs;
            #pragma unroll
            for (int ni = 0; ni < 4; ++ni) oacc[ni][r] *= alpha;
        }

        // P: C-layout -> A-layout via wave-private LDS slab
        #pragma unroll
        for (int ni = 0; ni < 4; ++ni)
            #pragma unroll
            for (int r = 0; r < 4; ++r)
                Ps[wrow0 + quad * 4 + r][ni * 16 + li] = f2b(p[ni][r]);

        bf16x8 pa0 = *(const bf16x8*)&Ps[wrow0 + li][quad * 8];
        bf16x8 pa1 = *(const bf16x8*)&Ps[wrow0 + li][32 + quad * 8];

        // O += P @ V
        #pragma unroll
        for (int ni = 0; ni < 4; ++ni) {
            bf16x8 v0 = *(const bf16x8*)&Vt[ni * 16 + li][quad * 8];
            bf16x8 v1 = *(const bf16x8*)&Vt[ni * 16 + li][32 + quad * 8];
            oacc[ni] = mfma16(pa0, v0, oacc[ni]);
            oacc[ni] = mfma16(pa1, v1, oacc[ni]);
        }
    }

    #pragma unroll
    for (int ni = 0; ni < 4; ++ni)
        #pragma unroll
        for (int r = 0; r < 4; ++r) {
            const int qg = qt * 64 + wrow0 + quad * 4 + r;
            obuf[((size_t)b * S_LEN + qg) * DM + h * HS + ni * 16 + li] =
                f2b(oacc[ni][r] / l_i[r]);
        }
}

extern "C" void kernel_launch(void* const* d_in, const int* in_sizes, int n_in,
                              void* d_out, int out_size, void* d_ws, size_t ws_size,
                              hipStream_t stream) {
    const float* x  = (const float*)d_in[0];
    const float* cq = (const float*)d_in[1];
    const float* sq = (const float*)d_in[2];
    const float* ck = (const float*)d_in[3];
    const float* sk = (const float*)d_in[4];
    // d_in[5]: causal tril mask (int32) — structure known, not re-read
    const float* Wp = (const float*)d_in[6];
    const float* bp = (const float*)d_in[7];
    const float* Wf = (const float*)d_in[8];
    const float* bf = (const float*)d_in[9];

    float* out  = (float*)d_out;
    float* ffo  = out;                 // (B,S,DM) fp32
    float* kout = out + 4194304;       // kv[0] = pre-rotary k (B,NH,S,HS) fp32
    float* vout = out + 8388608;       // kv[1] = v fp32

    uint16_t* qbuf = (uint16_t*)d_ws;  // RoPE'd q bf16
    uint16_t* kbuf = qbuf + 4194304;   // RoPE'd k bf16
    uint16_t* abuf = kbuf + 4194304;   // attn_o bf16
    uint16_t* WpT  = abuf;             // alias: dead before attn writes abuf
    uint16_t* WfT  = qbuf;             // alias: qbuf dead after attn

    dim3 blk(256);
    transpose_w<<<dim3(96, 32), blk, 0, stream>>>(Wp, WpT, 3072);
    gemm_mfma<0, false><<<dim3(24, 32), blk, 0, stream>>>(
        x, WpT, bp, 3072, cq, sq, ck, sk,
        qbuf, kbuf, kout, vout, nullptr);
    attn_mfma<<<dim3(1024), blk, 0, stream>>>(qbuf, kbuf, vout, abuf);
    transpose_w<<<dim3(32, 32), blk, 0, stream>>>(Wf, WfT, 1024);
    gemm_mfma<1, true><<<dim3(8, 32), blk, 0, stream>>>(
        abuf, WfT, bf, 1024, nullptr, nullptr, nullptr, nullptr,
        nullptr, nullptr, nullptr, nullptr, ffo);
}